// Round 13
// baseline (1569.235 us; speedup 1.0000x reference)
//
#include <hip/hip_runtime.h>

// SolvGNNV6 round 13: r10 best (transposed bucket, BK=64 swizzled GEMM;
// CSR variant of r12 reverted — scan overhead outweighed scatter savings)
// + 8-wide neighbor batching in gather_h (MLP test: 8 outstanding row loads).

#define NN 81920     // nodes per side
#define NN2 163840   // merged nodes (cat | an+NN)
#define NE 327680    // edges per side
#define NE2 655360
#define NB 2048      // graphs per side
#define NB2 4096
#define H 256
#define INDIM 74
#define KPAD 128     // first-conv K padded 74 -> 128
#define ZK 576       // MLP1 K padded 520 -> 576 (9 * 64)
#define DEGCAP 32    // max in-degree bucket (Poisson(4); P(>32) ~ 1e-19)
#define CPITCH 132   // C-tile LDS pitch (u16) for gemm epilogue

typedef unsigned short u16;
typedef __attribute__((ext_vector_type(8))) short short8;  // 8 bf16 (4 VGPRs)
typedef __attribute__((ext_vector_type(4))) float f32x4;

__device__ inline u16 f2b(float f) {  // fp32 -> bf16 bits, RNE
    unsigned u = __builtin_bit_cast(unsigned, f);
    u += 0x7fffu + ((u >> 16) & 1u);
    return (u16)(u >> 16);
}
__device__ inline float b2f(u16 b) {
    unsigned u = ((unsigned)b) << 16;
    return __builtin_bit_cast(float, u);
}
__device__ inline float blo(unsigned u) { return __builtin_bit_cast(float, u << 16); }
__device__ inline float bhi(unsigned u) { return __builtin_bit_cast(float, u & 0xffff0000u); }

// ---------- merged degree count + transposed bucket fill ----------
__global__ void fill_kernel(const int* __restrict__ cs, const int* __restrict__ cd,
                            const int* __restrict__ as_, const int* __restrict__ ad,
                            int* __restrict__ dego, int* __restrict__ cnti,
                            int* __restrict__ bucket) {
    int e = blockIdx.x * 256 + threadIdx.x;
    if (e < NE2) {
        int s, d;
        if (e < NE) { s = cs[e]; d = cd[e]; }
        else        { s = as_[e - NE] + NN; d = ad[e - NE] + NN; }
        atomicAdd(&dego[s], 1);
        int p = atomicAdd(&cnti[d], 1);
        if (p < DEGCAP) bucket[(size_t)p * NN2 + d] = s;
    }
}

__global__ void rsqrt_kernel(const int* __restrict__ dego, const int* __restrict__ cnti,
                             float* __restrict__ rso, float* __restrict__ rsi) {
    int i = blockIdx.x * 256 + threadIdx.x;
    if (i < NN2) {
        rso[i] = rsqrtf((float)(dego[i] > 1 ? dego[i] : 1));
        rsi[i] = rsqrtf((float)(cnti[i] > 1 ? cnti[i] : 1));
    }
}

// ---------- prescale x by rso -> bf16, pad rows to 128 cols (256 B aligned) ----------
__global__ __launch_bounds__(256) void prescale_x_kernel(
        const float* __restrict__ cx, const float* __restrict__ ax,
        const float* __restrict__ rso, u16* __restrict__ xbp) {
    int t = threadIdx.x;
    int node = blockIdx.x * 4 + (t >> 6);
    int lane = t & 63;                    // 64 u32 = 128 u16 per row
    const float* x = (node < NN) ? (cx + (size_t)node * INDIM)
                                 : (ax + (size_t)(node - NN) * INDIM);
    float w = rso[node];
    int f0 = lane * 2, f1 = f0 + 1;
    u16 a = (f0 < INDIM) ? f2b(x[f0] * w) : (u16)0;
    u16 b = (f1 < INDIM) ? f2b(x[f1] * w) : (u16)0;
    ((unsigned*)xbp)[(size_t)node * 64 + lane] = a | ((unsigned)b << 16);
}

// ---------- first-conv aggregation: 16 lanes/node, transposed-bucket reads ----------
__global__ __launch_bounds__(256) void gather_x_kernel(
        const u16* __restrict__ xbp, const int* __restrict__ bucket,
        const int* __restrict__ cnti, const float* __restrict__ rsi,
        u16* __restrict__ out) {
    int node = blockIdx.x * 16 + (threadIdx.x >> 4);
    int fc = (threadIdx.x & 15) * 8;      // 8 bf16 = 16 B per thread
    int deg = cnti[node]; if (deg > DEGCAP) deg = DEGCAP;
    const int* bk = bucket + node;        // stride NN2 per slot
    float acc[8] = {};
    for (int base = 0; base < deg; base += 4) {
        int i0 = bk[(size_t)base * NN2];
        int i1 = (base + 1 < deg) ? bk[(size_t)(base + 1) * NN2] : i0;
        int i2 = (base + 2 < deg) ? bk[(size_t)(base + 2) * NN2] : i0;
        int i3 = (base + 3 < deg) ? bk[(size_t)(base + 3) * NN2] : i0;
        float m1 = (base + 1 < deg) ? 1.f : 0.f;
        float m2 = (base + 2 < deg) ? 1.f : 0.f;
        float m3 = (base + 3 < deg) ? 1.f : 0.f;
        uint4 v0 = *(const uint4*)(xbp + (size_t)i0 * KPAD + fc);
        uint4 v1 = *(const uint4*)(xbp + (size_t)i1 * KPAD + fc);
        uint4 v2 = *(const uint4*)(xbp + (size_t)i2 * KPAD + fc);
        uint4 v3 = *(const uint4*)(xbp + (size_t)i3 * KPAD + fc);
        acc[0] += blo(v0.x) + m1 * blo(v1.x) + m2 * blo(v2.x) + m3 * blo(v3.x);
        acc[1] += bhi(v0.x) + m1 * bhi(v1.x) + m2 * bhi(v2.x) + m3 * bhi(v3.x);
        acc[2] += blo(v0.y) + m1 * blo(v1.y) + m2 * blo(v2.y) + m3 * blo(v3.y);
        acc[3] += bhi(v0.y) + m1 * bhi(v1.y) + m2 * bhi(v2.y) + m3 * bhi(v3.y);
        acc[4] += blo(v0.z) + m1 * blo(v1.z) + m2 * blo(v2.z) + m3 * blo(v3.z);
        acc[5] += bhi(v0.z) + m1 * bhi(v1.z) + m2 * bhi(v2.z) + m3 * bhi(v3.z);
        acc[6] += blo(v0.w) + m1 * blo(v1.w) + m2 * blo(v2.w) + m3 * blo(v3.w);
        acc[7] += bhi(v0.w) + m1 * bhi(v1.w) + m2 * bhi(v2.w) + m3 * bhi(v3.w);
    }
    float ri = rsi[node];
    u16 o[8];
#pragma unroll
    for (int i = 0; i < 8; ++i) o[i] = f2b(acc[i] * ri);
    uint4 ov;
    ov.x = o[0] | ((unsigned)o[1] << 16);
    ov.y = o[2] | ((unsigned)o[3] << 16);
    ov.z = o[4] | ((unsigned)o[5] << 16);
    ov.w = o[6] | ((unsigned)o[7] << 16);
    *(uint4*)(out + (size_t)node * KPAD + fc) = ov;
}

// ---------- H-dim aggregation, 8-wide neighbor batching (MLP test) ----------
__global__ __launch_bounds__(256) void gather_h_kernel(
        const u16* __restrict__ h, const int* __restrict__ bucket,
        const int* __restrict__ cnti, const float* __restrict__ rso,
        const float* __restrict__ rsi, u16* __restrict__ out) {
    int node = blockIdx.x * 8 + (threadIdx.x >> 5);
    int fc = (threadIdx.x & 31) * 8;     // 8 bf16 = 16 B per thread
    int deg = cnti[node]; if (deg > DEGCAP) deg = DEGCAP;
    const int* bk = bucket + node;
    float acc[8] = {};
    for (int base = 0; base < deg; base += 8) {
        int idx[8];
        float w[8];
#pragma unroll
        for (int j = 0; j < 8; ++j) {
            bool live = (base + j < deg) || (j == 0);
            idx[j] = live ? bk[(size_t)(base + j) * NN2] : idx[0];
        }
#pragma unroll
        for (int j = 0; j < 8; ++j)
            w[j] = (base + j < deg) ? rso[idx[j]] : 0.f;
        uint4 v[8];
#pragma unroll
        for (int j = 0; j < 8; ++j)
            v[j] = *(const uint4*)(h + (size_t)idx[j] * H + fc);
#pragma unroll
        for (int j = 0; j < 8; ++j) {
            acc[0] += blo(v[j].x) * w[j];
            acc[1] += bhi(v[j].x) * w[j];
            acc[2] += blo(v[j].y) * w[j];
            acc[3] += bhi(v[j].y) * w[j];
            acc[4] += blo(v[j].z) * w[j];
            acc[5] += bhi(v[j].z) * w[j];
            acc[6] += blo(v[j].w) * w[j];
            acc[7] += bhi(v[j].w) * w[j];
        }
    }
    float ri = rsi[node];
    u16 o[8];
#pragma unroll
    for (int i = 0; i < 8; ++i) o[i] = f2b(acc[i] * ri);
    uint4 ov;
    ov.x = o[0] | ((unsigned)o[1] << 16);
    ov.y = o[2] | ((unsigned)o[3] << 16);
    ov.z = o[4] | ((unsigned)o[5] << 16);
    ov.w = o[6] | ((unsigned)o[7] << 16);
    *(uint4*)(out + (size_t)node * H + fc) = ov;
}

// ---------- weight prep: fp32 row-major -> bf16 transposed ----------
__global__ void prep_w0_kernel(const float* __restrict__ W0, u16* __restrict__ Wt0) {
    int i = blockIdx.x * 256 + threadIdx.x;  // 256*128
    int n = i >> 7, k = i & 127;
    float v = (k < INDIM) ? W0[(size_t)k * H + n] : 0.f;
    Wt0[i] = f2b(v);
}

__global__ void prep_gcr_kernel(const float* __restrict__ W, u16* __restrict__ Wt) {
    int i = blockIdx.x * 256 + threadIdx.x;  // 65536 per layer
    int l = blockIdx.y;                      // 0..9
    int n = i >> 8, k = i & 255;
    Wt[(size_t)l * 65536 + i] = f2b(W[(size_t)l * 65536 + (size_t)k * H + n]);
}

__global__ void prep_w1_kernel(const float* __restrict__ W, u16* __restrict__ Wt) {
    int i = blockIdx.x * 256 + threadIdx.x;  // 1024 * 576
    if (i >= 1024 * ZK) return;
    int n = i / ZK, k = i - n * ZK;
    float v = (k < 520) ? W[(size_t)k * 1024 + n] : 0.f;
    Wt[i] = f2b(v);
}

__global__ void prep_w2_kernel(const float* __restrict__ W, u16* __restrict__ Wt) {
    int i = blockIdx.x * 256 + threadIdx.x;  // 512 * 1024
    int n = i >> 10, k = i & 1023;
    Wt[i] = f2b(W[(size_t)k * 512 + n]);
}

// ---------- bf16 MFMA GEMM helpers ----------
__device__ inline void ldg_lds16(const u16* g, u16* l) {
    __builtin_amdgcn_global_load_lds(
        (const __attribute__((address_space(1))) unsigned int*)g,
        (__attribute__((address_space(3))) unsigned int*)l, 16, 0, 0);
}
__device__ inline float actf(float v, int act) {
    if (act == 1) return fmaxf(v, 0.f);
    if (act == 2) return (v > 0.f) ? v : 0.01f * v;
    return v;
}

// ---------- 128x128 MFMA GEMM, BK=64, XOR-swizzled staging ----------
__global__ __launch_bounds__(256) void gemm_mfma_kernel(
        const u16* __restrict__ A, int lda,
        const u16* __restrict__ Bt, int ldb,
        const float* __restrict__ bias, u16* __restrict__ C, int ldc,
        int Kiters, int act) {   // Kiters = K/64
    __shared__ __align__(16) u16 smem[128 * CPITCH];  // 33 KB; overlays As/Bs
    u16* As = smem;           // 128 x 64 u16 = 16 KB
    u16* Bs = smem + 8192;    // 16 KB
    int t = threadIdx.x;
    int wave = t >> 6, lane = t & 63;
    int wr = wave >> 1, wc = wave & 1;
    int row0 = blockIdx.y * 128, col0 = blockIdx.x * 128;

    int sr = t >> 3;                       // 0..31
    int ksrc = (((t & 7) ^ (sr & 7))) * 8; // swizzled source k-offset (elems)
    const u16* Ag[4];
    const u16* Bg[4];
#pragma unroll
    for (int c = 0; c < 4; ++c) {
        Ag[c] = A + (size_t)(row0 + c * 32 + sr) * lda + ksrc;
        Bg[c] = Bt + (size_t)(col0 + c * 32 + sr) * ldb + ksrc;
    }
    u16* AsW = As + wave * 512;   // wave-uniform LDS base (HW adds lane*16)
    u16* BsW = Bs + wave * 512;

    f32x4 acc[4][4] = {};
    int mrow = lane & 15;
    int q = lane >> 4;            // 0..3

    for (int kt = 0; kt < Kiters; ++kt) {
#pragma unroll
        for (int c = 0; c < 4; ++c) ldg_lds16(Ag[c], AsW + c * 2048);
#pragma unroll
        for (int c = 0; c < 4; ++c) ldg_lds16(Bg[c], BsW + c * 2048);
        __syncthreads();
#pragma unroll
        for (int kk = 0; kk < 2; ++kk) {
            short8 a[4], b[4];
#pragma unroll
            for (int mt = 0; mt < 4; ++mt) {
                int row = wr * 64 + mt * 16 + mrow;
                int seg = (kk * 4 + q) ^ (row & 7);
                a[mt] = *(const short8*)(As + row * 64 + seg * 8);
            }
#pragma unroll
            for (int nt = 0; nt < 4; ++nt) {
                int row = wc * 64 + nt * 16 + mrow;
                int seg = (kk * 4 + q) ^ (row & 7);
                b[nt] = *(const short8*)(Bs + row * 64 + seg * 8);
            }
#pragma unroll
            for (int mt = 0; mt < 4; ++mt)
#pragma unroll
                for (int nt = 0; nt < 4; ++nt)
                    acc[mt][nt] = __builtin_amdgcn_mfma_f32_16x16x32_bf16(
                        a[mt], b[nt], acc[mt][nt], 0, 0, 0);
        }
        __syncthreads();
#pragma unroll
        for (int c = 0; c < 4; ++c) { Ag[c] += 64; Bg[c] += 64; }
    }

    // epilogue: stage C tile in LDS (CPITCH), coalesced dwordx4 stores
#pragma unroll
    for (int mt = 0; mt < 4; ++mt) {
        int rl = wr * 64 + mt * 16 + q * 4;
#pragma unroll
        for (int nt = 0; nt < 4; ++nt) {
            int cl = wc * 64 + nt * 16 + mrow;
            float bv = bias[col0 + cl];
#pragma unroll
            for (int qq = 0; qq < 4; ++qq) {
                float v = actf(acc[mt][nt][qq] + bv, act);
                smem[(size_t)(rl + qq) * CPITCH + cl] = f2b(v);
            }
        }
    }
    __syncthreads();
    int rr = t >> 4;
    int seg = t & 15;
#pragma unroll
    for (int pass = 0; pass < 8; ++pass) {
        int row = pass * 16 + rr;
        uint4 val = *(const uint4*)(smem + (size_t)row * CPITCH + seg * 8);
        *(uint4*)(C + (size_t)(row0 + row) * ldc + col0 + seg * 8) = val;
    }
}

// ---------- pooling (merged): graph g in [0,4096) -> z[g&2047, (g>>11)*256+] ----------
__global__ __launch_bounds__(256) void pool_kernel(const u16* __restrict__ h,
                                                   u16* __restrict__ z) {
    int g = blockIdx.x, f = threadIdx.x;
    float acc = 0.f;
    const u16* base = h + (size_t)g * 40 * H + f;
#pragma unroll
    for (int j = 0; j < 40; ++j) acc += b2f(base[j * H]);
    int zrow = g & (NB - 1);
    int zoff = (g >> 11) * H;
    z[(size_t)zrow * ZK + zoff + f] = f2b(acc);
}

__global__ void copy_add_kernel(const float* __restrict__ add, u16* __restrict__ z) {
    int i = blockIdx.x * 256 + threadIdx.x;
    if (i < NB * 8) {
        int g = i >> 3, a = i & 7;
        z[(size_t)g * ZK + 512 + a] = f2b(add[i]);
    }
}

// ---------- final GEMV: out[r] = sum_k m2b[r,k]*w[k] + b ----------
__global__ void gemv_out_kernel(const u16* __restrict__ A, const float* __restrict__ w,
                                const float* __restrict__ b, float* __restrict__ out, int K) {
    int wave = threadIdx.x >> 6;
    int lane = threadIdx.x & 63;
    int row = blockIdx.x * 4 + wave;
    float acc = 0.f;
    for (int k = lane; k < K; k += 64) acc += b2f(A[(size_t)row * K + k]) * w[k];
#pragma unroll
    for (int off = 32; off > 0; off >>= 1) acc += __shfl_down(acc, off, 64);
    if (lane == 0) out[row] = acc + b[0];
}

extern "C" void kernel_launch(void* const* d_in, const int* in_sizes, int n_in,
                              void* d_out, int out_size, void* d_ws, size_t ws_size,
                              hipStream_t stream) {
    const int*   cat_src = (const int*)d_in[0];
    const int*   cat_dst = (const int*)d_in[1];
    const float* cat_x   = (const float*)d_in[3];
    const int*   an_src  = (const int*)d_in[4];
    const int*   an_dst  = (const int*)d_in[5];
    const float* an_x    = (const float*)d_in[7];
    const float* add_f   = (const float*)d_in[8];
    const float* W0      = (const float*)d_in[9];
    const float* b0      = (const float*)d_in[10];
    const float* gcrW    = (const float*)d_in[11];
    const float* gcrb    = (const float*)d_in[12];
    const float* mW1     = (const float*)d_in[13];
    const float* mb1     = (const float*)d_in[14];
    const float* mW2     = (const float*)d_in[15];
    const float* mb2     = (const float*)d_in[16];
    const float* mW3     = (const float*)d_in[17];
    const float* mb3     = (const float*)d_in[18];
    float* out = (float*)d_out;

    // ---- workspace carve (~205 MB; xbp/aggx alias hA/hB dead ranges) ----
    char* p = (char*)d_ws;
    auto alloc = [&](size_t bytes) -> void* {
        void* rp = (void*)p;
        p += (bytes + 255) & ~(size_t)255;
        return rp;
    };
    int*   dego   = (int*)alloc((size_t)NN2 * 4);
    int*   cnti   = (int*)alloc((size_t)NN2 * 4);
    int*   bucket = (int*)alloc((size_t)NN2 * DEGCAP * 4);
    float* rso    = (float*)alloc((size_t)NN2 * 4);
    float* rsi    = (float*)alloc((size_t)NN2 * 4);
    u16*   hA     = (u16*)alloc((size_t)NN2 * H * 2);   // 84 MB
    u16*   hB     = (u16*)alloc((size_t)NN2 * H * 2);   // 84 MB
    u16*   Wt0    = (u16*)alloc((size_t)H * KPAD * 2);
    u16*   Wtg    = (u16*)alloc((size_t)10 * H * H * 2);
    u16*   Wt1    = (u16*)alloc((size_t)1024 * ZK * 2);
    u16*   Wt2    = (u16*)alloc((size_t)512 * 1024 * 2);
    u16*   zb     = (u16*)alloc((size_t)NB * ZK * 2);
    u16*   m1b    = (u16*)alloc((size_t)NB * 1024 * 2);
    u16*   m2b    = (u16*)alloc((size_t)NB * 512 * 2);
    u16*   xbp    = hA;   // NN2*KPAD*2 = 42 MB, dead after gather_x
    u16*   aggx   = hB;   // NN2*KPAD*2 = 42 MB, dead after first GEMM
    (void)ws_size; (void)in_sizes; (void)n_in; (void)out_size;

    // weight prep (bf16 transposed)
    prep_w0_kernel<<<(H * KPAD) / 256, 256, 0, stream>>>(W0, Wt0);
    prep_gcr_kernel<<<dim3(H * H / 256, 10), 256, 0, stream>>>(gcrW, Wtg);
    prep_w1_kernel<<<(1024 * ZK + 255) / 256, 256, 0, stream>>>(mW1, Wt1);
    prep_w2_kernel<<<(512 * 1024) / 256, 256, 0, stream>>>(mW2, Wt2);
    hipMemsetAsync(zb, 0, (size_t)NB * ZK * 2, stream);  // zero K-pad cols
    hipMemsetAsync(dego, 0, (size_t)NN2 * 4, stream);
    hipMemsetAsync(cnti, 0, (size_t)NN2 * 4, stream);

    // merged graph prep
    fill_kernel<<<NE2 / 256, 256, 0, stream>>>(cat_src, cat_dst, an_src, an_dst,
                                               dego, cnti, bucket);
    rsqrt_kernel<<<NN2 / 256, 256, 0, stream>>>(dego, cnti, rso, rsi);

    // first conv (merged): prescale (padded rows) -> gather -> GEMM K=128
    prescale_x_kernel<<<NN2 / 4, 256, 0, stream>>>(cat_x, an_x, rso, xbp);
    gather_x_kernel<<<NN2 / 16, 256, 0, stream>>>(xbp, bucket, cnti, rsi, aggx);
    gemm_mfma_kernel<<<dim3(H / 128, NN2 / 128), 256, 0, stream>>>(
        aggx, KPAD, Wt0, KPAD, b0, hA, H, KPAD / 64, 0);

    // 10 conv layers (merged): gather hA->hB, GEMM hB->hA
    for (int l = 0; l < 10; ++l) {
        gather_h_kernel<<<NN2 / 8, 256, 0, stream>>>(hA, bucket, cnti, rso, rsi, hB);
        gemm_mfma_kernel<<<dim3(H / 128, NN2 / 128), 256, 0, stream>>>(
            hB, H, Wtg + (size_t)l * H * H, H, gcrb + (size_t)l * H, hA, H,
            H / 64, 1);
    }
    pool_kernel<<<NB2, 256, 0, stream>>>(hA, zb);
    copy_add_kernel<<<(NB * 8 + 255) / 256, 256, 0, stream>>>(add_f, zb);

    // MLP head (bf16 MFMA)
    gemm_mfma_kernel<<<dim3(1024 / 128, NB / 128), 256, 0, stream>>>(
        zb, ZK, Wt1, ZK, mb1, m1b, 1024, ZK / 64, 2);
    gemm_mfma_kernel<<<dim3(512 / 128, NB / 128), 256, 0, stream>>>(
        m1b, 1024, Wt2, 1024, mb2, m2b, 512, 1024 / 64, 2);
    gemv_out_kernel<<<NB / 4, 256, 0, stream>>>(m2b, mW3, mb3, out, 512);
}

// Round 14
// 1489.693 us; speedup vs baseline: 1.0534x; 1.0534x over previous
//
#include <hip/hip_runtime.h>

// SolvGNNV6 FINAL (= round 10 best, 1488 us): merged cation+anion pipeline,
// transposed bucket fill, 4-wide-batched gathers, BK=64 XOR-swizzled MFMA
// GEMM (col-fastest grid), bf16 MLP head, fp32 GEMV out.
// Measured ceilings: gather_h 62us@4.1TB/s random-read equilibrium (4-wide
// beats simple and 8-wide — r13); conv GEMM at 168MB streaming floor; fill at
// cross-XCD write-allocate floor (bucket/CSR variants all measured r9-r12).

#define NN 81920     // nodes per side
#define NN2 163840   // merged nodes (cat | an+NN)
#define NE 327680    // edges per side
#define NE2 655360
#define NB 2048      // graphs per side
#define NB2 4096
#define H 256
#define INDIM 74
#define KPAD 128     // first-conv K padded 74 -> 128
#define ZK 576       // MLP1 K padded 520 -> 576 (9 * 64)
#define DEGCAP 32    // max in-degree bucket (Poisson(4); P(>32) ~ 1e-19)
#define CPITCH 132   // C-tile LDS pitch (u16) for gemm epilogue

typedef unsigned short u16;
typedef __attribute__((ext_vector_type(8))) short short8;  // 8 bf16 (4 VGPRs)
typedef __attribute__((ext_vector_type(4))) float f32x4;

__device__ inline u16 f2b(float f) {  // fp32 -> bf16 bits, RNE
    unsigned u = __builtin_bit_cast(unsigned, f);
    u += 0x7fffu + ((u >> 16) & 1u);
    return (u16)(u >> 16);
}
__device__ inline float b2f(u16 b) {
    unsigned u = ((unsigned)b) << 16;
    return __builtin_bit_cast(float, u);
}
__device__ inline float blo(unsigned u) { return __builtin_bit_cast(float, u << 16); }
__device__ inline float bhi(unsigned u) { return __builtin_bit_cast(float, u & 0xffff0000u); }

// ---------- merged degree count + transposed bucket fill ----------
__global__ void fill_kernel(const int* __restrict__ cs, const int* __restrict__ cd,
                            const int* __restrict__ as_, const int* __restrict__ ad,
                            int* __restrict__ dego, int* __restrict__ cnti,
                            int* __restrict__ bucket) {
    int e = blockIdx.x * 256 + threadIdx.x;
    if (e < NE2) {
        int s, d;
        if (e < NE) { s = cs[e]; d = cd[e]; }
        else        { s = as_[e - NE] + NN; d = ad[e - NE] + NN; }
        atomicAdd(&dego[s], 1);
        int p = atomicAdd(&cnti[d], 1);
        if (p < DEGCAP) bucket[(size_t)p * NN2 + d] = s;
    }
}

__global__ void rsqrt_kernel(const int* __restrict__ dego, const int* __restrict__ cnti,
                             float* __restrict__ rso, float* __restrict__ rsi) {
    int i = blockIdx.x * 256 + threadIdx.x;
    if (i < NN2) {
        rso[i] = rsqrtf((float)(dego[i] > 1 ? dego[i] : 1));
        rsi[i] = rsqrtf((float)(cnti[i] > 1 ? cnti[i] : 1));
    }
}

// ---------- prescale x by rso -> bf16, pad rows to 128 cols (256 B aligned) ----------
__global__ __launch_bounds__(256) void prescale_x_kernel(
        const float* __restrict__ cx, const float* __restrict__ ax,
        const float* __restrict__ rso, u16* __restrict__ xbp) {
    int t = threadIdx.x;
    int node = blockIdx.x * 4 + (t >> 6);
    int lane = t & 63;                    // 64 u32 = 128 u16 per row
    const float* x = (node < NN) ? (cx + (size_t)node * INDIM)
                                 : (ax + (size_t)(node - NN) * INDIM);
    float w = rso[node];
    int f0 = lane * 2, f1 = f0 + 1;
    u16 a = (f0 < INDIM) ? f2b(x[f0] * w) : (u16)0;
    u16 b = (f1 < INDIM) ? f2b(x[f1] * w) : (u16)0;
    ((unsigned*)xbp)[(size_t)node * 64 + lane] = a | ((unsigned)b << 16);
}

// ---------- first-conv aggregation: 16 lanes/node, transposed-bucket reads ----------
__global__ __launch_bounds__(256) void gather_x_kernel(
        const u16* __restrict__ xbp, const int* __restrict__ bucket,
        const int* __restrict__ cnti, const float* __restrict__ rsi,
        u16* __restrict__ out) {
    int node = blockIdx.x * 16 + (threadIdx.x >> 4);
    int fc = (threadIdx.x & 15) * 8;      // 8 bf16 = 16 B per thread
    int deg = cnti[node]; if (deg > DEGCAP) deg = DEGCAP;
    const int* bk = bucket + node;        // stride NN2 per slot
    float acc[8] = {};
    for (int base = 0; base < deg; base += 4) {
        int i0 = bk[(size_t)base * NN2];
        int i1 = (base + 1 < deg) ? bk[(size_t)(base + 1) * NN2] : i0;
        int i2 = (base + 2 < deg) ? bk[(size_t)(base + 2) * NN2] : i0;
        int i3 = (base + 3 < deg) ? bk[(size_t)(base + 3) * NN2] : i0;
        float m1 = (base + 1 < deg) ? 1.f : 0.f;
        float m2 = (base + 2 < deg) ? 1.f : 0.f;
        float m3 = (base + 3 < deg) ? 1.f : 0.f;
        uint4 v0 = *(const uint4*)(xbp + (size_t)i0 * KPAD + fc);
        uint4 v1 = *(const uint4*)(xbp + (size_t)i1 * KPAD + fc);
        uint4 v2 = *(const uint4*)(xbp + (size_t)i2 * KPAD + fc);
        uint4 v3 = *(const uint4*)(xbp + (size_t)i3 * KPAD + fc);
        acc[0] += blo(v0.x) + m1 * blo(v1.x) + m2 * blo(v2.x) + m3 * blo(v3.x);
        acc[1] += bhi(v0.x) + m1 * bhi(v1.x) + m2 * bhi(v2.x) + m3 * bhi(v3.x);
        acc[2] += blo(v0.y) + m1 * blo(v1.y) + m2 * blo(v2.y) + m3 * blo(v3.y);
        acc[3] += bhi(v0.y) + m1 * bhi(v1.y) + m2 * bhi(v2.y) + m3 * bhi(v3.y);
        acc[4] += blo(v0.z) + m1 * blo(v1.z) + m2 * blo(v2.z) + m3 * blo(v3.z);
        acc[5] += bhi(v0.z) + m1 * bhi(v1.z) + m2 * bhi(v2.z) + m3 * bhi(v3.z);
        acc[6] += blo(v0.w) + m1 * blo(v1.w) + m2 * blo(v2.w) + m3 * blo(v3.w);
        acc[7] += bhi(v0.w) + m1 * bhi(v1.w) + m2 * bhi(v2.w) + m3 * bhi(v3.w);
    }
    float ri = rsi[node];
    u16 o[8];
#pragma unroll
    for (int i = 0; i < 8; ++i) o[i] = f2b(acc[i] * ri);
    uint4 ov;
    ov.x = o[0] | ((unsigned)o[1] << 16);
    ov.y = o[2] | ((unsigned)o[3] << 16);
    ov.z = o[4] | ((unsigned)o[5] << 16);
    ov.w = o[6] | ((unsigned)o[7] << 16);
    *(uint4*)(out + (size_t)node * KPAD + fc) = ov;
}

// ---------- H-dim aggregation, 4-wide neighbor batching ----------
__global__ __launch_bounds__(256) void gather_h_kernel(
        const u16* __restrict__ h, const int* __restrict__ bucket,
        const int* __restrict__ cnti, const float* __restrict__ rso,
        const float* __restrict__ rsi, u16* __restrict__ out) {
    int node = blockIdx.x * 8 + (threadIdx.x >> 5);
    int fc = (threadIdx.x & 31) * 8;     // 8 bf16 = 16 B per thread
    int deg = cnti[node]; if (deg > DEGCAP) deg = DEGCAP;
    const int* bk = bucket + node;
    float acc[8] = {};
    for (int base = 0; base < deg; base += 4) {
        int i0 = bk[(size_t)base * NN2];
        int i1 = (base + 1 < deg) ? bk[(size_t)(base + 1) * NN2] : i0;
        int i2 = (base + 2 < deg) ? bk[(size_t)(base + 2) * NN2] : i0;
        int i3 = (base + 3 < deg) ? bk[(size_t)(base + 3) * NN2] : i0;
        float w0 = rso[i0];
        float w1 = (base + 1 < deg) ? rso[i1] : 0.f;
        float w2 = (base + 2 < deg) ? rso[i2] : 0.f;
        float w3 = (base + 3 < deg) ? rso[i3] : 0.f;
        uint4 v0 = *(const uint4*)(h + (size_t)i0 * H + fc);
        uint4 v1 = *(const uint4*)(h + (size_t)i1 * H + fc);
        uint4 v2 = *(const uint4*)(h + (size_t)i2 * H + fc);
        uint4 v3 = *(const uint4*)(h + (size_t)i3 * H + fc);
        acc[0] += blo(v0.x) * w0 + blo(v1.x) * w1 + blo(v2.x) * w2 + blo(v3.x) * w3;
        acc[1] += bhi(v0.x) * w0 + bhi(v1.x) * w1 + bhi(v2.x) * w2 + bhi(v3.x) * w3;
        acc[2] += blo(v0.y) * w0 + blo(v1.y) * w1 + blo(v2.y) * w2 + blo(v3.y) * w3;
        acc[3] += bhi(v0.y) * w0 + bhi(v1.y) * w1 + bhi(v2.y) * w2 + bhi(v3.y) * w3;
        acc[4] += blo(v0.z) * w0 + blo(v1.z) * w1 + blo(v2.z) * w2 + blo(v3.z) * w3;
        acc[5] += bhi(v0.z) * w0 + bhi(v1.z) * w1 + bhi(v2.z) * w2 + bhi(v3.z) * w3;
        acc[6] += blo(v0.w) * w0 + blo(v1.w) * w1 + blo(v2.w) * w2 + blo(v3.w) * w3;
        acc[7] += bhi(v0.w) * w0 + bhi(v1.w) * w1 + bhi(v2.w) * w2 + bhi(v3.w) * w3;
    }
    float ri = rsi[node];
    u16 o[8];
#pragma unroll
    for (int i = 0; i < 8; ++i) o[i] = f2b(acc[i] * ri);
    uint4 ov;
    ov.x = o[0] | ((unsigned)o[1] << 16);
    ov.y = o[2] | ((unsigned)o[3] << 16);
    ov.z = o[4] | ((unsigned)o[5] << 16);
    ov.w = o[6] | ((unsigned)o[7] << 16);
    *(uint4*)(out + (size_t)node * H + fc) = ov;
}

// ---------- weight prep: fp32 row-major -> bf16 transposed ----------
__global__ void prep_w0_kernel(const float* __restrict__ W0, u16* __restrict__ Wt0) {
    int i = blockIdx.x * 256 + threadIdx.x;  // 256*128
    int n = i >> 7, k = i & 127;
    float v = (k < INDIM) ? W0[(size_t)k * H + n] : 0.f;
    Wt0[i] = f2b(v);
}

__global__ void prep_gcr_kernel(const float* __restrict__ W, u16* __restrict__ Wt) {
    int i = blockIdx.x * 256 + threadIdx.x;  // 65536 per layer
    int l = blockIdx.y;                      // 0..9
    int n = i >> 8, k = i & 255;
    Wt[(size_t)l * 65536 + i] = f2b(W[(size_t)l * 65536 + (size_t)k * H + n]);
}

__global__ void prep_w1_kernel(const float* __restrict__ W, u16* __restrict__ Wt) {
    int i = blockIdx.x * 256 + threadIdx.x;  // 1024 * 576
    if (i >= 1024 * ZK) return;
    int n = i / ZK, k = i - n * ZK;
    float v = (k < 520) ? W[(size_t)k * 1024 + n] : 0.f;
    Wt[i] = f2b(v);
}

__global__ void prep_w2_kernel(const float* __restrict__ W, u16* __restrict__ Wt) {
    int i = blockIdx.x * 256 + threadIdx.x;  // 512 * 1024
    int n = i >> 10, k = i & 1023;
    Wt[i] = f2b(W[(size_t)k * 512 + n]);
}

// ---------- bf16 MFMA GEMM helpers ----------
__device__ inline void ldg_lds16(const u16* g, u16* l) {
    __builtin_amdgcn_global_load_lds(
        (const __attribute__((address_space(1))) unsigned int*)g,
        (__attribute__((address_space(3))) unsigned int*)l, 16, 0, 0);
}
__device__ inline float actf(float v, int act) {
    if (act == 1) return fmaxf(v, 0.f);
    if (act == 2) return (v > 0.f) ? v : 0.01f * v;
    return v;
}

// ---------- 128x128 MFMA GEMM, BK=64, XOR-swizzled staging ----------
// LDS slot (row, seg) holds global k-seg (seg ^ (row&7)) -> staging stays
// linear (global_load_lds constraint) while fragment reads are bank-clean.
// grid (N/128, M/128): col fastest -> A-tile re-read L2/LLC-hot.
__global__ __launch_bounds__(256) void gemm_mfma_kernel(
        const u16* __restrict__ A, int lda,
        const u16* __restrict__ Bt, int ldb,
        const float* __restrict__ bias, u16* __restrict__ C, int ldc,
        int Kiters, int act) {   // Kiters = K/64
    __shared__ __align__(16) u16 smem[128 * CPITCH];  // 33 KB; overlays As/Bs
    u16* As = smem;           // 128 x 64 u16 = 16 KB
    u16* Bs = smem + 8192;    // 16 KB
    int t = threadIdx.x;
    int wave = t >> 6, lane = t & 63;
    int wr = wave >> 1, wc = wave & 1;
    int row0 = blockIdx.y * 128, col0 = blockIdx.x * 128;

    int sr = t >> 3;                       // 0..31
    int ksrc = (((t & 7) ^ (sr & 7))) * 8; // swizzled source k-offset (elems)
    const u16* Ag[4];
    const u16* Bg[4];
#pragma unroll
    for (int c = 0; c < 4; ++c) {
        Ag[c] = A + (size_t)(row0 + c * 32 + sr) * lda + ksrc;
        Bg[c] = Bt + (size_t)(col0 + c * 32 + sr) * ldb + ksrc;
    }
    u16* AsW = As + wave * 512;   // wave-uniform LDS base (HW adds lane*16)
    u16* BsW = Bs + wave * 512;

    f32x4 acc[4][4] = {};
    int mrow = lane & 15;
    int q = lane >> 4;            // 0..3

    for (int kt = 0; kt < Kiters; ++kt) {
#pragma unroll
        for (int c = 0; c < 4; ++c) ldg_lds16(Ag[c], AsW + c * 2048);
#pragma unroll
        for (int c = 0; c < 4; ++c) ldg_lds16(Bg[c], BsW + c * 2048);
        __syncthreads();
#pragma unroll
        for (int kk = 0; kk < 2; ++kk) {
            short8 a[4], b[4];
#pragma unroll
            for (int mt = 0; mt < 4; ++mt) {
                int row = wr * 64 + mt * 16 + mrow;
                int seg = (kk * 4 + q) ^ (row & 7);
                a[mt] = *(const short8*)(As + row * 64 + seg * 8);
            }
#pragma unroll
            for (int nt = 0; nt < 4; ++nt) {
                int row = wc * 64 + nt * 16 + mrow;
                int seg = (kk * 4 + q) ^ (row & 7);
                b[nt] = *(const short8*)(Bs + row * 64 + seg * 8);
            }
#pragma unroll
            for (int mt = 0; mt < 4; ++mt)
#pragma unroll
                for (int nt = 0; nt < 4; ++nt)
                    acc[mt][nt] = __builtin_amdgcn_mfma_f32_16x16x32_bf16(
                        a[mt], b[nt], acc[mt][nt], 0, 0, 0);
        }
        __syncthreads();
#pragma unroll
        for (int c = 0; c < 4; ++c) { Ag[c] += 64; Bg[c] += 64; }
    }

    // epilogue: stage C tile in LDS (CPITCH), coalesced dwordx4 stores
#pragma unroll
    for (int mt = 0; mt < 4; ++mt) {
        int rl = wr * 64 + mt * 16 + q * 4;
#pragma unroll
        for (int nt = 0; nt < 4; ++nt) {
            int cl = wc * 64 + nt * 16 + mrow;
            float bv = bias[col0 + cl];
#pragma unroll
            for (int qq = 0; qq < 4; ++qq) {
                float v = actf(acc[mt][nt][qq] + bv, act);
                smem[(size_t)(rl + qq) * CPITCH + cl] = f2b(v);
            }
        }
    }
    __syncthreads();
    int rr = t >> 4;
    int seg = t & 15;
#pragma unroll
    for (int pass = 0; pass < 8; ++pass) {
        int row = pass * 16 + rr;
        uint4 val = *(const uint4*)(smem + (size_t)row * CPITCH + seg * 8);
        *(uint4*)(C + (size_t)(row0 + row) * ldc + col0 + seg * 8) = val;
    }
}

// ---------- pooling (merged): graph g in [0,4096) -> z[g&2047, (g>>11)*256+] ----------
__global__ __launch_bounds__(256) void pool_kernel(const u16* __restrict__ h,
                                                   u16* __restrict__ z) {
    int g = blockIdx.x, f = threadIdx.x;
    float acc = 0.f;
    const u16* base = h + (size_t)g * 40 * H + f;
#pragma unroll
    for (int j = 0; j < 40; ++j) acc += b2f(base[j * H]);
    int zrow = g & (NB - 1);
    int zoff = (g >> 11) * H;
    z[(size_t)zrow * ZK + zoff + f] = f2b(acc);
}

__global__ void copy_add_kernel(const float* __restrict__ add, u16* __restrict__ z) {
    int i = blockIdx.x * 256 + threadIdx.x;
    if (i < NB * 8) {
        int g = i >> 3, a = i & 7;
        z[(size_t)g * ZK + 512 + a] = f2b(add[i]);
    }
}

// ---------- final GEMV: out[r] = sum_k m2b[r,k]*w[k] + b ----------
__global__ void gemv_out_kernel(const u16* __restrict__ A, const float* __restrict__ w,
                                const float* __restrict__ b, float* __restrict__ out, int K) {
    int wave = threadIdx.x >> 6;
    int lane = threadIdx.x & 63;
    int row = blockIdx.x * 4 + wave;
    float acc = 0.f;
    for (int k = lane; k < K; k += 64) acc += b2f(A[(size_t)row * K + k]) * w[k];
#pragma unroll
    for (int off = 32; off > 0; off >>= 1) acc += __shfl_down(acc, off, 64);
    if (lane == 0) out[row] = acc + b[0];
}

extern "C" void kernel_launch(void* const* d_in, const int* in_sizes, int n_in,
                              void* d_out, int out_size, void* d_ws, size_t ws_size,
                              hipStream_t stream) {
    const int*   cat_src = (const int*)d_in[0];
    const int*   cat_dst = (const int*)d_in[1];
    const float* cat_x   = (const float*)d_in[3];
    const int*   an_src  = (const int*)d_in[4];
    const int*   an_dst  = (const int*)d_in[5];
    const float* an_x    = (const float*)d_in[7];
    const float* add_f   = (const float*)d_in[8];
    const float* W0      = (const float*)d_in[9];
    const float* b0      = (const float*)d_in[10];
    const float* gcrW    = (const float*)d_in[11];
    const float* gcrb    = (const float*)d_in[12];
    const float* mW1     = (const float*)d_in[13];
    const float* mb1     = (const float*)d_in[14];
    const float* mW2     = (const float*)d_in[15];
    const float* mb2     = (const float*)d_in[16];
    const float* mW3     = (const float*)d_in[17];
    const float* mb3     = (const float*)d_in[18];
    float* out = (float*)d_out;

    // ---- workspace carve (~205 MB; xbp/aggx alias hA/hB dead ranges) ----
    char* p = (char*)d_ws;
    auto alloc = [&](size_t bytes) -> void* {
        void* rp = (void*)p;
        p += (bytes + 255) & ~(size_t)255;
        return rp;
    };
    int*   dego   = (int*)alloc((size_t)NN2 * 4);
    int*   cnti   = (int*)alloc((size_t)NN2 * 4);
    int*   bucket = (int*)alloc((size_t)NN2 * DEGCAP * 4);
    float* rso    = (float*)alloc((size_t)NN2 * 4);
    float* rsi    = (float*)alloc((size_t)NN2 * 4);
    u16*   hA     = (u16*)alloc((size_t)NN2 * H * 2);   // 84 MB
    u16*   hB     = (u16*)alloc((size_t)NN2 * H * 2);   // 84 MB
    u16*   Wt0    = (u16*)alloc((size_t)H * KPAD * 2);
    u16*   Wtg    = (u16*)alloc((size_t)10 * H * H * 2);
    u16*   Wt1    = (u16*)alloc((size_t)1024 * ZK * 2);
    u16*   Wt2    = (u16*)alloc((size_t)512 * 1024 * 2);
    u16*   zb     = (u16*)alloc((size_t)NB * ZK * 2);
    u16*   m1b    = (u16*)alloc((size_t)NB * 1024 * 2);
    u16*   m2b    = (u16*)alloc((size_t)NB * 512 * 2);
    u16*   xbp    = hA;   // NN2*KPAD*2 = 42 MB, dead after gather_x
    u16*   aggx   = hB;   // NN2*KPAD*2 = 42 MB, dead after first GEMM
    (void)ws_size; (void)in_sizes; (void)n_in; (void)out_size;

    // weight prep (bf16 transposed)
    prep_w0_kernel<<<(H * KPAD) / 256, 256, 0, stream>>>(W0, Wt0);
    prep_gcr_kernel<<<dim3(H * H / 256, 10), 256, 0, stream>>>(gcrW, Wtg);
    prep_w1_kernel<<<(1024 * ZK + 255) / 256, 256, 0, stream>>>(mW1, Wt1);
    prep_w2_kernel<<<(512 * 1024) / 256, 256, 0, stream>>>(mW2, Wt2);
    hipMemsetAsync(zb, 0, (size_t)NB * ZK * 2, stream);  // zero K-pad cols
    hipMemsetAsync(dego, 0, (size_t)NN2 * 4, stream);
    hipMemsetAsync(cnti, 0, (size_t)NN2 * 4, stream);

    // merged graph prep
    fill_kernel<<<NE2 / 256, 256, 0, stream>>>(cat_src, cat_dst, an_src, an_dst,
                                               dego, cnti, bucket);
    rsqrt_kernel<<<NN2 / 256, 256, 0, stream>>>(dego, cnti, rso, rsi);

    // first conv (merged): prescale (padded rows) -> gather -> GEMM K=128
    prescale_x_kernel<<<NN2 / 4, 256, 0, stream>>>(cat_x, an_x, rso, xbp);
    gather_x_kernel<<<NN2 / 16, 256, 0, stream>>>(xbp, bucket, cnti, rsi, aggx);
    gemm_mfma_kernel<<<dim3(H / 128, NN2 / 128), 256, 0, stream>>>(
        aggx, KPAD, Wt0, KPAD, b0, hA, H, KPAD / 64, 0);

    // 10 conv layers (merged): gather hA->hB, GEMM hB->hA
    for (int l = 0; l < 10; ++l) {
        gather_h_kernel<<<NN2 / 8, 256, 0, stream>>>(hA, bucket, cnti, rso, rsi, hB);
        gemm_mfma_kernel<<<dim3(H / 128, NN2 / 128), 256, 0, stream>>>(
            hB, H, Wtg + (size_t)l * H * H, H, gcrb + (size_t)l * H, hA, H,
            H / 64, 1);
    }
    pool_kernel<<<NB2, 256, 0, stream>>>(hA, zb);
    copy_add_kernel<<<(NB * 8 + 255) / 256, 256, 0, stream>>>(add_f, zb);

    // MLP head (bf16 MFMA)
    gemm_mfma_kernel<<<dim3(1024 / 128, NB / 128), 256, 0, stream>>>(
        zb, ZK, Wt1, ZK, mb1, m1b, 1024, ZK / 64, 2);
    gemm_mfma_kernel<<<dim3(512 / 128, NB / 128), 256, 0, stream>>>(
        m1b, 1024, Wt2, 1024, mb2, m2b, 512, 1024 / 64, 2);
    gemv_out_kernel<<<NB / 4, 256, 0, stream>>>(m2b, mW3, mb3, out, 512);
}